// Round 9
// baseline (4461.093 us; speedup 1.0000x reference)
//
#include <hip/hip_runtime.h>
#include <stdint.h>

#define T_MAX 512
#define BATCH 64
#define NCLS  128
#define BEAM  32
#define TBL   6144
#define NEGF  (-1e30f)
#define EMPTYK ((int)0x80000000)
#define HPRIME 1000003u
#define SCAP  256

// jnp.logaddexp: max + log1p(exp(-|a-b|)) (all values finite here)
__device__ __forceinline__ float lae(float a, float b) {
  float mx = fmaxf(a, b);
  return mx + log1pf(expf(-fabsf(a - b)));
}
// monotonic float <-> uint mapping for ordering / atomicMax on floats
__device__ __forceinline__ unsigned encf(float x) {
  unsigned v = __float_as_uint(x);
  return (v & 0x80000000u) ? ~v : (v | 0x80000000u);
}
__device__ __forceinline__ float decf(unsigned u) {
  unsigned v = (u & 0x80000000u) ? (u ^ 0x80000000u) : ~u;
  return __uint_as_float(v);
}
__device__ __forceinline__ unsigned lowkey(unsigned h) {
  return 0xFFFFFFFFu - (h ^ 0x80000000u);   // smaller signed hash ranks higher
}

__device__ __forceinline__ int tbl_insert(int* key, int h) {
  unsigned x = (unsigned)h * 2654435761u;
  x ^= x >> 16;
  int j = (int)(((unsigned long long)x * (unsigned long long)TBL) >> 32);
  for (;;) {
    int cur = key[j];
    if (cur == EMPTYK) cur = atomicCAS(&key[j], EMPTYK, h);
    if (cur == EMPTYK || cur == h) return j;
    ++j; if (j == TBL) j = 0;
  }
}

__device__ __forceinline__ unsigned long long shflx64(unsigned long long v, int m) {
  unsigned lo = (unsigned)__shfl_xor((int)(unsigned)v, m, 64);
  unsigned hi = (unsigned)__shfl_xor((int)(unsigned)(v >> 32), m, 64);
  return ((unsigned long long)hi << 32) | lo;
}

__global__ __launch_bounds__(64, 1)
void ctc_beam_kernel(const float* __restrict__ data,
                     const int* __restrict__ dlen,
                     int* __restrict__ out) {
  // rare-path hash table — touched only on anomalies / overflow
  __shared__ int       tkey[TBL];
  __shared__ unsigned  tmax[TBL];
  __shared__ unsigned  tsum[TBL];
  __shared__ unsigned  tmin[TBL];
  __shared__ unsigned short bp[T_MAX * BEAM];  // backptr: parent|cls<<5|ext<<12
  __shared__ __align__(16) float lpbuf[2][NCLS];
  __shared__ int   bhash[2][BEAM];
  __shared__ float bpb[2][BEAM], bpnb[2][BEAM];
  __shared__ int   blen[2][BEAM], blast[2][BEAM];
  __shared__ float sptot[BEAM], s_pb[BEAM], s_pnb[BEAM], s_pnbm[BEAM];
  __shared__ int   stay_slot[BEAM];
  __shared__ unsigned char mergeTo[BEAM * NCLS];  // 0xFF = not merged
  __shared__ int mergeCnt[BEAM], mergeFrom[BEAM];
  __shared__ unsigned thsub[64];          // [0..31]=stay keys, [32..63]=parentBest
  __shared__ unsigned long long skey[SCAP + 16];  // +16 pad for batched reads
  __shared__ unsigned sidx[SCAP];
  __shared__ unsigned sel[BEAM];
  __shared__ int seqbuf[T_MAX];
  __shared__ int flen_s;

  const int tid = threadIdx.x;   // 0..63, one wave
  const int b = blockIdx.x;
  int L = dlen[b];
  L = L < 0 ? 0 : (L > T_MAX ? T_MAX : L);

  if (tid < BEAM) {
    bhash[0][tid] = tid;
    bpb[0][tid]   = (tid == 0) ? 0.0f : NEGF;
    bpnb[0][tid]  = NEGF;
    blen[0][tid]  = 0;
    blast[0][tid] = -1;
    mergeCnt[tid] = 0;
  }
  {
    unsigned* mtw = (unsigned*)mergeTo;
    for (int m = tid; m < (BEAM * NCLS) / 4; m += 64) mtw[m] = 0xFFFFFFFFu;
  }
  if (L > 0) {
    lpbuf[0][tid * 2 + 0] = data[(size_t)b * NCLS + tid * 2 + 0];
    lpbuf[0][tid * 2 + 1] = data[(size_t)b * NCLS + tid * 2 + 1];
  }
  __syncthreads();

  int cb = 0;
  for (int t = 0; t < L; ++t) {
    const int par = t & 1;
    const bool haspre = (t + 1 < L);
    float2 pf = make_float2(0.f, 0.f);
    if (haspre)
      pf = *(const float2*)(data + ((size_t)(t + 1) * BATCH + b) * NCLS + tid * 2);
    float* lpc = lpbuf[par];
    int anomr = 0;   // register anomaly flag

    // ======== phase D: stays + exact merge detection (R5 verbatim) ========
    if (tid < BEAM) {
      const float pbv = bpb[cb][tid], pnbv = bpnb[cb][tid];
      const float pt = lae(pbv, pnbv);
      sptot[tid] = pt;
      s_pb[tid]  = pt + lpc[0];
      const int lsti = blast[cb][tid];
      s_pnb[tid] = pnbv + ((lsti >= 0) ? lpc[lsti] : NEGF);
      thsub[32 + tid] = 0u;
    }
    for (int k = tid; k < BEAM * BEAM; k += 64) {
      const int j = k >> 5, i2 = k & 31;
      const unsigned hj = (unsigned)bhash[cb][j];
      const unsigned hip = (unsigned)bhash[cb][i2] * HPRIME;
      const unsigned c = hj - hip - 1u;
      if (c < (unsigned)NCLS) {                 // extend(i2,c) merges stay j
        atomicAdd(&mergeCnt[j], 1);
        mergeFrom[j] = (i2 << 8) | (int)c;
        mergeTo[i2 * NCLS + (int)c] = (unsigned char)j;
      }
      if (j < i2) {                              // extend-extend collision?
        const unsigned d = (hj - (unsigned)bhash[cb][i2]) * HPRIME;
        if (d + 127u <= 254u) anomr = 1;
      }
    }
    __syncthreads();  // A

    // ======== phase K: extend keys (64 classes/thread) + parent best + stays ==
    const int i  = tid >> 1;
    const int c0 = (tid & 1) << 6;
    unsigned e32[64];
    unsigned hbr;
    {
      const float pbi = bpb[cb][i];
      const float pti = sptot[i];
      const int   lsti = blast[cb][i];
      hbr = (unsigned)bhash[cb][i] * HPRIME;
      const float4* lp4 = (const float4*)(lpc + c0);
      const unsigned* mw = (const unsigned*)&mergeTo[i * NCLS + c0];
      unsigned pbest = 0u;
      #pragma unroll
      for (int g = 0; g < 8; ++g) {
        const float4 l0 = lp4[g * 2], l1 = lp4[g * 2 + 1];
        const float lv[8] = {l0.x, l0.y, l0.z, l0.w, l1.x, l1.y, l1.z, l1.w};
        const unsigned m0 = mw[g * 2], m1 = mw[g * 2 + 1];
        #pragma unroll
        for (int k = 0; k < 8; ++k) {
          const int c = c0 + g * 8 + k;
          const unsigned mb = ((k < 4 ? (m0 >> (8 * k)) : (m1 >> (8 * (k - 4)))) & 0xFFu);
          const float x = (c == 0) ? NEGF : (((c == lsti) ? pbi : pti) + lv[k]);
          const float tot = fmaxf(x, NEGF);   // == lae(NEGF,x) bitwise
          unsigned enc = encf(tot);
          if (mb != 0xFFu || c == 0) enc = 0u;  // merged into a stay, or blank
          e32[g * 8 + k] = enc;
          pbest = pbest > enc ? pbest : enc;
        }
      }
      atomicMax(&thsub[32 + i], pbest);
    }
    if (tid < BEAM) {
      const int j = tid;
      if (mergeCnt[j] > 1) anomr = 1;
      float pnbm;
      if (mergeCnt[j] == 1) {
        const int mf = mergeFrom[j];
        const int mi = mf >> 8, mc = mf & 255;
        const float e = (mc == 0) ? NEGF
            : (((mc == blast[cb][mi]) ? bpb[cb][mi] : sptot[mi]) + lpc[mc]);
        const float a = s_pnb[j];
        const float m = fmaxf(a, e);
        const float s = expf(a - m) + expf(e - m);  // stay term first (ref order)
        pnbm = m + logf(s);
      } else {
        pnbm = s_pnb[j];
      }
      s_pnbm[j] = pnbm;
      thsub[j] = encf(lae(s_pb[j], pnbm));
    }
    __syncthreads();  // B

    // ======== theta (all lanes, R5 rank formula) + filter (scan compaction) ===
    const bool an = (__any(anomr) != 0);
    bool dorare = an;
    int scr = 0;
    if (!an) {
      const unsigned vq = thsub[tid];
      int rank = 0;
      #pragma unroll
      for (int p2 = 0; p2 < 64; ++p2) {
        const unsigned vp = thsub[p2];
        rank += (vp > vq || (vp == vq && p2 < tid)) ? 1 : 0;
      }
      const unsigned long long rb = __ballot(rank == 31);
      const int rsrc = __ffsll((long long)rb) - 1;
      const unsigned thr = (unsigned)__shfl((int)vq, rsrc, 64);

      const bool stayS = (tid < BEAM) && (thsub[tid] >= thr);
      int myn = stayS ? 1 : 0;
      #pragma unroll
      for (int k = 0; k < 64; ++k) myn += (e32[k] >= thr) ? 1 : 0;
      int pfx = myn;
      #pragma unroll
      for (int d = 1; d < 64; d <<= 1) {
        const int o = __shfl_up(pfx, d, 64);
        if (tid >= d) pfx += o;
      }
      scr = __shfl(pfx, 63, 64);
      if (scr <= SCAP) {
        int o = pfx - myn;
        #pragma unroll
        for (int k = 0; k < 64; ++k) {
          if (e32[k] >= thr) {
            skey[o] = ((unsigned long long)e32[k] << 32) |
                      (unsigned long long)lowkey(hbr + (unsigned)(c0 + k + 1));
            sidx[o] = (unsigned)(BEAM + i * NCLS + (c0 + k));
            ++o;
          }
        }
        if (stayS) {
          skey[o] = ((unsigned long long)thsub[tid] << 32) |
                    (unsigned long long)lowkey((unsigned)bhash[cb][tid]);
          sidx[o] = (unsigned)tid;
        }
      } else {
        dorare = true;
      }
    }
    __syncthreads();  // D

    if (!dorare) {
      // ======== phase R: rank-by-count (R7-proven), update + clears ========
      for (int s0 = tid; s0 < scr; s0 += 64) {
        const unsigned long long kq = skey[s0];
        int rank = 0;
        for (int p0 = 0; p0 < scr; p0 += 16) {
          #pragma unroll
          for (int pp2 = 0; pp2 < 16; ++pp2) {
            const unsigned long long kp = skey[p0 + pp2];   // padded, in-bounds
            rank += ((p0 + pp2) < scr && kp > kq) ? 1 : 0;
          }
        }
        if (rank < BEAM) {
          const int j = rank;
          const unsigned s = sidx[s0];
          int nh, pq, cls, ex; float npb, npnb;
          if (s < BEAM) {                     // stay-rooted segment
            pq = (int)s; cls = 0; ex = 0;
            nh = bhash[cb][pq];
            npb = s_pb[pq];
            npnb = s_pnbm[pq];
          } else {                            // standalone extend
            const unsigned q = s - BEAM;
            pq = (int)(q >> 7); cls = (int)(q & 127); ex = 1;
            nh = (int)((unsigned)bhash[cb][pq] * HPRIME + (unsigned)(cls + 1));
            npb = NEGF;
            npnb = (cls == 0) ? NEGF
                 : (((cls == blast[cb][pq]) ? bpb[cb][pq] : sptot[pq]) + lpc[cls]);
          }
          const int plen = blen[cb][pq], plast = blast[cb][pq];
          const int nb2 = cb ^ 1;
          bhash[nb2][j] = nh; bpb[nb2][j] = npb; bpnb[nb2][j] = npnb;
          blen[nb2][j]  = plen + ex;
          blast[nb2][j] = ex ? cls : plast;
          bp[t * BEAM + j] = (unsigned short)(pq | (cls << 5) | (ex << 12));
        }
      }
      {
        unsigned* mtw = (unsigned*)mergeTo;
        #pragma unroll
        for (int m = 0; m < 16; ++m) mtw[tid + m * 64] = 0xFFFFFFFFu;
      }
      if (tid < BEAM) mergeCnt[tid] = 0;
      if (haspre) {
        lpbuf[par ^ 1][tid * 2 + 0] = pf.x;
        lpbuf[par ^ 1][tid * 2 + 1] = pf.y;
      }
      __syncthreads();  // E
    } else {
      // ================= RARE PATH: full hash table (R1/R5 semantics) ========
      for (int m = tid; m < TBL; m += 64) {
        tkey[m] = EMPTYK; tmax[m] = 0u; tsum[m] = 0u; tmin[m] = 0xFFFFFFFFu;
      }
      __syncthreads();
      {
        const float pbi = bpb[cb][i];
        const float pti = sptot[i];
        const int   lsti = blast[cb][i];
        #pragma unroll 1
        for (int k = 0; k < 64; ++k) {
          const int c = c0 + k;
          int h = (int)(hbr + (unsigned)(c + 1));
          if (h == EMPTYK) h = (int)0x80000001u;
          const float x = (c == 0) ? NEGF : (((c == lsti) ? pbi : pti) + lpc[c]);
          const int s = tbl_insert(tkey, h);
          atomicMax(&tmax[s], encf(x));
          atomicMin(&tmin[s], (unsigned)(BEAM + i * NCLS + c));
        }
      }
      if (tid < BEAM) {
        const int s = tbl_insert(tkey, bhash[cb][tid]);
        atomicMax(&tmax[s], encf(s_pnb[tid]));
        atomicMin(&tmin[s], (unsigned)tid);
        stay_slot[tid] = s;
      }
      __syncthreads();
      {
        const float pbi = bpb[cb][i];
        const float pti = sptot[i];
        const int   lsti = blast[cb][i];
        #pragma unroll 1
        for (int k = 0; k < 64; ++k) {
          const int c = c0 + k;
          int h = (int)(hbr + (unsigned)(c + 1));
          if (h == EMPTYK) h = (int)0x80000001u;
          const float x = (c == 0) ? NEGF : (((c == lsti) ? pbi : pti) + lpc[c]);
          const int s = tbl_insert(tkey, h);
          atomicAdd((float*)&tsum[s], expf(x - decf(tmax[s])));
        }
      }
      if (tid < BEAM) {
        const int s = stay_slot[tid];
        atomicAdd((float*)&tsum[s], expf(s_pnb[tid] - decf(tmax[s])));
      }
      __syncthreads();
      for (int m = tid; m < TBL; m += 64) {
        if (tkey[m] != EMPTYK) {
          const float mm = decf(tmax[m]);
          const float ss = __uint_as_float(tsum[m]);
          const float pnbm = mm + logf(ss);
          tmax[m] = __float_as_uint(pnbm);
          tsum[m] = encf(lae(NEGF, pnbm));
        }
      }
      __syncthreads();
      if (tid < BEAM) {
        const int s = stay_slot[tid];
        tsum[s] = encf(lae(s_pb[tid], __uint_as_float(tmax[s])));
      }
      __syncthreads();
      // ordered top-32 pop (keys unique: distinct hashes)
      for (int it = 0; it < BEAM; ++it) {
        unsigned long long bestk = 0ull; int bests = -1;
        #pragma unroll 4
        for (int q2 = 0; q2 < TBL / 64; ++q2) {
          const int idx = tid * (TBL / 64) + q2;
          if (tkey[idx] != EMPTYK && tsum[idx] != 0u) {
            const unsigned long long kk =
                ((unsigned long long)tsum[idx] << 32) |
                (unsigned long long)lowkey((unsigned)tkey[idx]);
            if (kk > bestk) { bestk = kk; bests = idx; }
          }
        }
        unsigned long long wm = bestk;
        #pragma unroll
        for (int off = 32; off > 0; off >>= 1) {
          const unsigned long long o = shflx64(wm, off);
          if (o > wm) wm = o;
        }
        const unsigned long long ball = __ballot(bestk == wm && wm != 0ull);
        const int winner = ball ? (__ffsll((long long)ball) - 1) : -1;
        if (tid == winner) { sel[it] = (unsigned)bests; tsum[bests] = 0u; }
        else if (winner < 0 && tid == 0) sel[it] = 0xFFFFFFFFu;
        __syncthreads();
      }
      if (tid < BEAM) {
        const int j = tid;
        const unsigned s = sel[j];
        int nh, pq, cls, ex; float npb, npnb;
        if (s != 0xFFFFFFFFu) {
          nh = tkey[s];
          npnb = __uint_as_float(tmax[s]);
          npb = NEGF;
          #pragma unroll
          for (int q2 = 0; q2 < BEAM; ++q2)
            if (stay_slot[q2] == (int)s) npb = s_pb[q2];
          const unsigned mi = tmin[s];
          ex  = (mi >= BEAM) ? 1 : 0;
          pq  = ex ? (int)((mi - BEAM) >> 7) : (int)mi;
          cls = ex ? (int)((mi - BEAM) & 127) : 0;
          pq &= 31;
        } else {
          nh = 0x7F000000 + j; npb = NEGF; npnb = NEGF; pq = j; cls = 0; ex = 0;
        }
        const int plen = blen[cb][pq], plast = blast[cb][pq];
        const int nb2 = cb ^ 1;
        bhash[nb2][j] = nh; bpb[nb2][j] = npb; bpnb[nb2][j] = npnb;
        blen[nb2][j]  = plen + ex;
        blast[nb2][j] = ex ? cls : plast;
        bp[t * BEAM + j] = (unsigned short)(pq | (cls << 5) | (ex << 12));
      }
      {
        unsigned* mtw = (unsigned*)mergeTo;
        for (int m = tid; m < (BEAM * NCLS) / 4; m += 64) mtw[m] = 0xFFFFFFFFu;
      }
      if (tid < BEAM) mergeCnt[tid] = 0;
      if (haspre) {
        lpbuf[par ^ 1][tid * 2 + 0] = pf.x;
        lpbuf[par ^ 1][tid * 2 + 1] = pf.y;
      }
      __syncthreads();
    }
    cb ^= 1;
  }

  // ---- final top-1 + path reconstruction via backpointers (R5 verbatim) ----
  if (tid == 0) {
    float bt = -3.4e38f; int bj = 0;
    for (int j = 0; j < BEAM; ++j) {
      const float tt = lae(bpb[cb][j], bpnb[cb][j]);
      if (tt > bt) { bt = tt; bj = j; }   // strict > : lowest index wins ties
    }
    int cur = bj;
    int pos = blen[cb][bj];
    flen_s = pos;
    for (int tt2 = L - 1; tt2 >= 0; --tt2) {
      const unsigned short e = bp[tt2 * BEAM + cur];
      const int pq = e & 31, cl = (e >> 5) & 127, exq = (e >> 12) & 1;
      if (exq) { --pos; if (pos >= 0) seqbuf[pos] = cl; }
      cur = pq;
    }
  }
  __syncthreads();
  const int fl = flen_s;
  #pragma unroll
  for (int k = 0; k < 8; ++k) {
    const int o = tid + k * 64;
    out[(size_t)b * T_MAX + o] = (o < fl) ? seqbuf[o] : 0;
  }
}

extern "C" void kernel_launch(void* const* d_in, const int* in_sizes, int n_in,
                              void* d_out, int out_size, void* d_ws, size_t ws_size,
                              hipStream_t stream) {
  const float* data = (const float*)d_in[0];   // [512, 64, 128] f32 log-probs
  const int*   dlen = (const int*)d_in[1];     // [64] int32
  int* out = (int*)d_out;                      // [64, 512] int32
  (void)in_sizes; (void)n_in; (void)out_size; (void)d_ws; (void)ws_size;
  hipLaunchKernelGGL(ctc_beam_kernel, dim3(BATCH), dim3(64), 0, stream,
                     data, dlen, out);
}

// Round 10
// 2886.503 us; speedup vs baseline: 1.5455x; 1.5455x over previous
//
#include <hip/hip_runtime.h>
#include <stdint.h>

#define T_MAX 512
#define BATCH 64
#define NCLS  128
#define BEAM  32
#define TBL   6144
#define NEGF  (-1e30f)
#define EMPTYK ((int)0x80000000)
#define HPRIME 1000003u
#define SCAP  256
#define NTHR  256

// jnp.logaddexp: max + log1p(exp(-|a-b|)) (all values finite here)
__device__ __forceinline__ float lae(float a, float b) {
  float mx = fmaxf(a, b);
  return mx + log1pf(expf(-fabsf(a - b)));
}
// monotonic float <-> uint mapping for ordering / atomicMax on floats
__device__ __forceinline__ unsigned encf(float x) {
  unsigned v = __float_as_uint(x);
  return (v & 0x80000000u) ? ~v : (v | 0x80000000u);
}
__device__ __forceinline__ float decf(unsigned u) {
  unsigned v = (u & 0x80000000u) ? (u ^ 0x80000000u) : ~u;
  return __uint_as_float(v);
}
__device__ __forceinline__ unsigned lowkey(unsigned h) {
  return 0xFFFFFFFFu - (h ^ 0x80000000u);   // smaller signed hash ranks higher
}

__device__ __forceinline__ int tbl_insert(int* key, int h) {
  unsigned x = (unsigned)h * 2654435761u;
  x ^= x >> 16;
  int j = (int)(((unsigned long long)x * (unsigned long long)TBL) >> 32);
  for (;;) {
    int cur = key[j];
    if (cur == EMPTYK) cur = atomicCAS(&key[j], EMPTYK, h);
    if (cur == EMPTYK || cur == h) return j;
    ++j; if (j == TBL) j = 0;
  }
}

__device__ __forceinline__ unsigned long long shflx64(unsigned long long v, int m) {
  unsigned lo = (unsigned)__shfl_xor((int)(unsigned)v, m, 64);
  unsigned hi = (unsigned)__shfl_xor((int)(unsigned)(v >> 32), m, 64);
  return ((unsigned long long)hi << 32) | lo;
}

__global__ __launch_bounds__(NTHR, 1)
void ctc_beam_kernel(const float* __restrict__ data,
                     const int* __restrict__ dlen,
                     int* __restrict__ out) {
  // rare-path hash table — touched only on anomalies / overflow
  __shared__ int       tkey[TBL];
  __shared__ unsigned  tmax[TBL];
  __shared__ unsigned  tsum[TBL];
  __shared__ unsigned  tmin[TBL];
  __shared__ unsigned short bp[T_MAX * BEAM];  // backptr: parent|cls<<5|ext<<12
  __shared__ __align__(16) float lpbuf[2][NCLS];
  __shared__ int   bhash[2][BEAM];
  __shared__ float bpb[2][BEAM], bpnb[2][BEAM];
  __shared__ int   blen[2][BEAM], blast[2][BEAM];
  __shared__ float sptot[BEAM], s_pb[BEAM], s_pnb[BEAM], s_pnbm[BEAM];
  __shared__ int   stay_slot[BEAM];
  __shared__ unsigned char mergeTo[BEAM * NCLS];  // 0xFF = not merged
  __shared__ int mergeCnt[BEAM], mergeFrom[BEAM];
  __shared__ unsigned thsub[64];          // [0..31]=stay keys, [32..63]=parentBest
  __shared__ int anom, ovf;
  __shared__ int scnt[2];                 // parity-buffered survivor count
  __shared__ unsigned thr_s;
  __shared__ unsigned long long skey[SCAP + 16];  // +16 pad for batched reads
  __shared__ unsigned sidx[SCAP];
  // rare-path selection scratch
  __shared__ unsigned long long wkey[4 * BEAM];
  __shared__ unsigned widx[4 * BEAM];
  __shared__ unsigned sel[BEAM];
  __shared__ int seqbuf[T_MAX];
  __shared__ int flen_s;

  const int tid = threadIdx.x;   // 0..255, 4 waves
  const int b = blockIdx.x;
  int L = dlen[b];
  L = L < 0 ? 0 : (L > T_MAX ? T_MAX : L);

  if (tid < BEAM) {
    bhash[0][tid] = tid;
    bpb[0][tid]   = (tid == 0) ? 0.0f : NEGF;
    bpnb[0][tid]  = NEGF;
    blen[0][tid]  = 0;
    blast[0][tid] = -1;
    mergeCnt[tid] = 0;
  }
  {
    unsigned* mtw = (unsigned*)mergeTo;
    for (int m = tid; m < (BEAM * NCLS) / 4; m += NTHR) mtw[m] = 0xFFFFFFFFu;
  }
  if (tid == 0) { anom = 0; ovf = 0; scnt[0] = 0; scnt[1] = 0; }
  if (tid < NCLS && L > 0) lpbuf[0][tid] = data[(size_t)b * NCLS + tid];
  __syncthreads();

  int cb = 0;
  for (int t = 0; t < L; ++t) {
    const int par = t & 1;
    const bool haspre = (tid >= 128) && (t + 1 < L);
    float pre = 0.0f;
    if (haspre) pre = data[((size_t)(t + 1) * BATCH + b) * NCLS + (tid - 128)];
    float* lpc = lpbuf[par];

    // ======== phase D: stays + exact merge detection + thsub hi-half clear ====
    if (tid < BEAM) {
      const float pbv = bpb[cb][tid], pnbv = bpnb[cb][tid];
      const float pt = lae(pbv, pnbv);
      sptot[tid] = pt;
      s_pb[tid]  = pt + lpc[0];
      const int lsti = blast[cb][tid];
      s_pnb[tid] = pnbv + ((lsti >= 0) ? lpc[lsti] : NEGF);
      thsub[32 + tid] = 0u;
    }
    for (int k = tid; k < BEAM * BEAM; k += NTHR) {
      const int j = k >> 5, i2 = k & 31;
      const unsigned hj = (unsigned)bhash[cb][j];
      const unsigned hip = (unsigned)bhash[cb][i2] * HPRIME;
      const unsigned c = hj - hip - 1u;
      if (c < (unsigned)NCLS) {                 // extend(i2,c) merges stay j
        atomicAdd(&mergeCnt[j], 1);
        mergeFrom[j] = (i2 << 8) | (int)c;
        mergeTo[i2 * NCLS + (int)c] = (unsigned char)j;
      }
      if (j < i2) {                              // extend-extend collision?
        const unsigned d = (hj - (unsigned)bhash[cb][i2]) * HPRIME;
        if (d + 127u <= 254u) anom = 1;
      }
    }
    __syncthreads();  // A

    // ======== phase K: extend keys (16 classes/thread) + parent best + stays ==
    const int i  = tid >> 3;
    const int c0 = (tid & 7) << 4;
    unsigned long long k16[16];
    {
      const float pbi = bpb[cb][i];
      const float pti = sptot[i];
      const int   lsti = blast[cb][i];
      const unsigned hb = (unsigned)bhash[cb][i] * HPRIME;
      const float4* lp4 = (const float4*)(lpc + c0);
      const unsigned* mw = (const unsigned*)&mergeTo[i * NCLS + c0];
      unsigned pbest = 0u;
      #pragma unroll
      for (int g = 0; g < 4; ++g) {
        const float4 lv4 = lp4[g];
        const unsigned mword = mw[g];
        const float lvv[4] = {lv4.x, lv4.y, lv4.z, lv4.w};
        #pragma unroll
        for (int k = 0; k < 4; ++k) {
          const int c = c0 + g * 4 + k;
          const unsigned mb = (mword >> (8 * k)) & 0xFFu;
          const float x = (c == 0) ? NEGF : (((c == lsti) ? pbi : pti) + lvv[k]);
          const float tot = fmaxf(x, NEGF);   // == lae(NEGF,x) bitwise
          const unsigned h = hb + (unsigned)(c + 1);
          unsigned long long key =
              ((unsigned long long)encf(tot) << 32) |
              (unsigned long long)lowkey(h);
          if (mb != 0xFFu || c == 0) key = 0ull;  // merged into a stay, or blank
          k16[g * 4 + k] = key;
          const unsigned e32 = (unsigned)(key >> 32);
          pbest = pbest > e32 ? pbest : e32;
        }
      }
      atomicMax(&thsub[32 + i], pbest);
    }
    if (tid < BEAM) {
      const int j = tid;
      if (mergeCnt[j] > 1) anom = 1;
      float pnbm;
      if (mergeCnt[j] == 1) {
        const int mf = mergeFrom[j];
        const int mi = mf >> 8, mc = mf & 255;
        const float e = (mc == 0) ? NEGF
            : (((mc == blast[cb][mi]) ? bpb[cb][mi] : sptot[mi]) + lpc[mc]);
        const float a = s_pnb[j];
        const float m = fmaxf(a, e);
        const float s = expf(a - m) + expf(e - m);  // stay term first (ref order)
        pnbm = m + logf(s);
      } else {
        pnbm = s_pnb[j];
      }
      s_pnbm[j] = pnbm;
      thsub[j] = encf(lae(s_pb[j], pnbm));
    }
    if (tid == NTHR - 1) scnt[par ^ 1] = 0;   // reset next step's counter
    __syncthreads();  // B

    const bool an = (anom != 0);
    bool dorare = an;
    if (!an) {
      // ======== phase T: wave0 ranks theta (fully unrolled); waves 1-3 reset ==
      if (tid < 64) {
        const unsigned vq = thsub[tid];
        int rank = 0;
        #pragma unroll
        for (int p = 0; p < 64; ++p) {
          const unsigned vp = thsub[p];
          rank += (vp > vq || (vp == vq && p < tid)) ? 1 : 0;
        }
        if (rank == 31) thr_s = vq;
      } else {
        unsigned* mtw = (unsigned*)mergeTo;
        for (int m = tid - 64; m < (BEAM * NCLS) / 4; m += (NTHR - 64))
          mtw[m] = 0xFFFFFFFFu;
        if (tid >= 64 && tid < 64 + BEAM) mergeCnt[tid - 64] = 0;
        if (haspre) lpbuf[par ^ 1][tid - 128] = pre;
      }
      __syncthreads();  // C

      // ======== phase F: filter + batched compaction ========
      const unsigned thr = thr_s;
      int myn = 0;
      #pragma unroll
      for (int k = 0; k < 16; ++k) myn += ((unsigned)(k16[k] >> 32) >= thr) ? 1 : 0;
      const bool stayS = (tid < BEAM) && (thsub[tid] >= thr);
      myn += stayS ? 1 : 0;
      if (myn) {
        int o = atomicAdd(&scnt[par], myn);
        if (o + myn <= SCAP) {
          #pragma unroll
          for (int k = 0; k < 16; ++k) {
            if ((unsigned)(k16[k] >> 32) >= thr) {
              skey[o] = k16[k];
              sidx[o] = (unsigned)(BEAM + i * NCLS + (c0 + k));
              ++o;
            }
          }
          if (stayS) {
            skey[o] = ((unsigned long long)thsub[tid] << 32) |
                      (unsigned long long)lowkey((unsigned)bhash[cb][tid]);
            sidx[o] = (unsigned)tid;
          }
        } else ovf = 1;
      }
      __syncthreads();  // D
      dorare = (ovf != 0);
    }

    if (!dorare) {
      // ======== phase R: rank-by-count (padded 16-batches); ranking thread
      //          updates beam directly ========
      const int scr = scnt[par];
      if (tid < scr) {
        const unsigned long long kq = skey[tid];
        int rank = 0;
        for (int p0 = 0; p0 < scr; p0 += 16) {
          #pragma unroll
          for (int pp = 0; pp < 16; ++pp) {
            const unsigned long long kp = skey[p0 + pp];   // padded, in-bounds
            rank += ((p0 + pp) < scr && kp > kq) ? 1 : 0;
          }
        }
        if (rank < BEAM) {
          const int j = rank;
          const unsigned s = sidx[tid];
          int nh, p, cls, ex; float npb, npnb;
          if (s < BEAM) {                     // stay-rooted segment
            p = (int)s; cls = 0; ex = 0;
            nh = bhash[cb][p];
            npb = s_pb[p];
            npnb = s_pnbm[p];
          } else {                            // standalone extend
            const unsigned q = s - BEAM;
            p = (int)(q >> 7); cls = (int)(q & 127); ex = 1;
            nh = (int)((unsigned)bhash[cb][p] * HPRIME + (unsigned)(cls + 1));
            npb = NEGF;
            npnb = (cls == 0) ? NEGF
                 : (((cls == blast[cb][p]) ? bpb[cb][p] : sptot[p]) + lpc[cls]);
          }
          const int plen = blen[cb][p], plast = blast[cb][p];
          const int nb = cb ^ 1;
          bhash[nb][j] = nh; bpb[nb][j] = npb; bpnb[nb][j] = npnb;
          blen[nb][j]  = plen + ex;
          blast[nb][j] = ex ? cls : plast;
          bp[t * BEAM + j] = (unsigned short)(p | (cls << 5) | (ex << 12));
        }
      }
      __syncthreads();  // E
    } else {
      // ================= RARE PATH: full hash table (proven R1 semantics) =====
      for (int m = tid; m < TBL; m += NTHR) {
        tkey[m] = EMPTYK; tmax[m] = 0u; tsum[m] = 0u; tmin[m] = 0xFFFFFFFFu;
      }
      __syncthreads();

      int eslot[16]; float ex_[16];
      {
        const float pbi = bpb[cb][i];
        const float pti = sptot[i];
        const int   lsti = blast[cb][i];
        const unsigned hb = (unsigned)bhash[cb][i] * HPRIME;
        #pragma unroll
        for (int k = 0; k < 16; ++k) {
          const int c = c0 + k;
          int h = (int)(hb + (unsigned)(c + 1));
          if (h == EMPTYK) h = (int)0x80000001u;
          const float x = (c == 0) ? NEGF : (((c == lsti) ? pbi : pti) + lpc[c]);
          const int s = tbl_insert(tkey, h);
          atomicMax(&tmax[s], encf(x));
          atomicMin(&tmin[s], (unsigned)(BEAM + i * NCLS + c));
          eslot[k] = s; ex_[k] = x;
        }
      }
      if (tid < BEAM) {
        const int s = tbl_insert(tkey, bhash[cb][tid]);
        atomicMax(&tmax[s], encf(s_pnb[tid]));
        atomicMin(&tmin[s], (unsigned)tid);
        stay_slot[tid] = s;
      }
      __syncthreads();

      #pragma unroll
      for (int k = 0; k < 16; ++k) {
        const int s = eslot[k];
        atomicAdd((float*)&tsum[s], expf(ex_[k] - decf(tmax[s])));
      }
      if (tid < BEAM) {
        const int s = stay_slot[tid];
        atomicAdd((float*)&tsum[s], expf(s_pnb[tid] - decf(tmax[s])));
      }
      __syncthreads();

      for (int m = tid; m < TBL; m += NTHR) {
        if (tkey[m] != EMPTYK) {
          const float mm = decf(tmax[m]);
          const float ss = __uint_as_float(tsum[m]);
          const float pnbm = mm + logf(ss);
          tmax[m] = __float_as_uint(pnbm);
          tsum[m] = encf(lae(NEGF, pnbm));
        }
      }
      __syncthreads();
      if (tid < BEAM) {
        const int s = stay_slot[tid];
        tsum[s] = encf(lae(s_pb[tid], __uint_as_float(tmax[s])));
      }
      __syncthreads();

      {
        const int wv = tid >> 6, ln = tid & 63;
        const int base = wv * (TBL / 4) + ln * (TBL / NTHR);
        unsigned long long kk2[TBL / NTHR];
        #pragma unroll
        for (int m = 0; m < TBL / NTHR; ++m) {
          const int idx = base + m;
          if (tkey[idx] != EMPTYK) {
            kk2[m] = ((unsigned long long)tsum[idx] << 32) |
                     (unsigned long long)lowkey((unsigned)tkey[idx]);
          } else kk2[m] = 0ull;
        }
        unsigned cons = 0;
        for (int it = 0; it < BEAM; ++it) {
          unsigned long long best = 0ull; int bi = -1;
          #pragma unroll
          for (int m = 0; m < TBL / NTHR; ++m)
            if (!((cons >> m) & 1u) && kk2[m] > best) { best = kk2[m]; bi = m; }
          unsigned long long wm = best;
          #pragma unroll
          for (int off = 32; off > 0; off >>= 1) {
            const unsigned long long o = shflx64(wm, off);
            if (o > wm) wm = o;
          }
          const unsigned long long ball = __ballot(best == wm && wm != 0ull);
          const int winner = ball ? (__ffsll((long long)ball) - 1) : -1;
          if (ln == winner) {
            cons |= 1u << bi;
            wkey[wv * BEAM + it] = wm;
            widx[wv * BEAM + it] = (unsigned)(base + bi);
          } else if (winner < 0 && ln == 0) {
            wkey[wv * BEAM + it] = 0ull;
            widx[wv * BEAM + it] = 0xFFFFFFFFu;
          }
        }
      }
      __syncthreads();
      if (tid < 64) {  // merge 4 sorted lists (2 consecutive entries per lane)
        unsigned long long mk[2]; unsigned mx[2];
        #pragma unroll
        for (int m = 0; m < 2; ++m) { mk[m] = wkey[tid * 2 + m]; mx[m] = widx[tid * 2 + m]; }
        unsigned cons = 0;
        for (int it = 0; it < BEAM; ++it) {
          unsigned long long best = 0ull; int bi = -1;
          #pragma unroll
          for (int m = 0; m < 2; ++m)
            if (!((cons >> m) & 1u) && mk[m] > best) { best = mk[m]; bi = m; }
          unsigned long long wm = best;
          #pragma unroll
          for (int off = 32; off > 0; off >>= 1) {
            const unsigned long long o = shflx64(wm, off);
            if (o > wm) wm = o;
          }
          const unsigned long long ball = __ballot(best == wm && wm != 0ull);
          const int winner = ball ? (__ffsll((long long)ball) - 1) : -1;
          if (tid == winner) { cons |= 1u << bi; sel[it] = mx[bi]; }
          else if (winner < 0 && tid == 0) sel[it] = 0xFFFFFFFFu;
        }
      }
      __syncthreads();

      if (tid < BEAM) {
        const int j = tid;
        const unsigned s = sel[j];
        int nh, p, cls, ex; float npb, npnb;
        if (s != 0xFFFFFFFFu) {
          nh = tkey[s];
          npnb = __uint_as_float(tmax[s]);
          npb = NEGF;
          #pragma unroll
          for (int q = 0; q < BEAM; ++q)
            if (stay_slot[q] == (int)s) npb = s_pb[q];
          const unsigned mi = tmin[s];
          ex  = (mi >= BEAM) ? 1 : 0;
          p   = ex ? (int)((mi - BEAM) >> 7) : (int)mi;
          cls = ex ? (int)((mi - BEAM) & 127) : 0;
          p &= 31;
        } else {
          nh = 0x7F000000 + j; npb = NEGF; npnb = NEGF; p = j; cls = 0; ex = 0;
        }
        const int plen = blen[cb][p], plast = blast[cb][p];
        const int nb = cb ^ 1;
        bhash[nb][j] = nh; bpb[nb][j] = npb; bpnb[nb][j] = npnb;
        blen[nb][j]  = plen + ex;
        blast[nb][j] = ex ? cls : plast;
        bp[t * BEAM + j] = (unsigned short)(p | (cls << 5) | (ex << 12));
      }
      // per-step resets (fast path does these in phase T)
      {
        unsigned* mtw = (unsigned*)mergeTo;
        for (int m = tid; m < (BEAM * NCLS) / 4; m += NTHR) mtw[m] = 0xFFFFFFFFu;
      }
      if (tid >= 64 && tid < 64 + BEAM) mergeCnt[tid - 64] = 0;
      if (tid == NTHR - 1) { anom = 0; ovf = 0; }
      if (haspre) lpbuf[par ^ 1][tid - 128] = pre;
      __syncthreads();
    }
    cb ^= 1;
  }

  // ---- final top-1 + path reconstruction via backpointers
  if (tid == 0) {
    float bt = -3.4e38f; int bj = 0;
    for (int j = 0; j < BEAM; ++j) {
      const float tt = lae(bpb[cb][j], bpnb[cb][j]);
      if (tt > bt) { bt = tt; bj = j; }   // strict > : lowest index wins ties
    }
    int cur = bj;
    int pos = blen[cb][bj];
    flen_s = pos;
    for (int tt = L - 1; tt >= 0; --tt) {
      const unsigned short e = bp[tt * BEAM + cur];
      const int p = e & 31, cl = (e >> 5) & 127, ex = (e >> 12) & 1;
      if (ex) { --pos; if (pos >= 0) seqbuf[pos] = cl; }
      cur = p;
    }
  }
  __syncthreads();
  const int fl = flen_s;
  for (int k = tid; k < T_MAX; k += NTHR) {
    out[(size_t)b * T_MAX + k] = (k < fl) ? seqbuf[k] : 0;
  }
}

extern "C" void kernel_launch(void* const* d_in, const int* in_sizes, int n_in,
                              void* d_out, int out_size, void* d_ws, size_t ws_size,
                              hipStream_t stream) {
  const float* data = (const float*)d_in[0];   // [512, 64, 128] f32 log-probs
  const int*   dlen = (const int*)d_in[1];     // [64] int32
  int* out = (int*)d_out;                      // [64, 512] int32
  (void)in_sizes; (void)n_in; (void)out_size; (void)d_ws; (void)ws_size;
  hipLaunchKernelGGL(ctc_beam_kernel, dim3(BATCH), dim3(NTHR), 0, stream,
                     data, dlen, out);
}

// Round 11
// 2217.752 us; speedup vs baseline: 2.0115x; 1.3015x over previous
//
#include <hip/hip_runtime.h>
#include <stdint.h>

#define T_MAX 512
#define BATCH 64
#define NCLS  128
#define BEAM  32
#define TBL   6144
#define NEGF  (-1e30f)
#define EMPTYK ((int)0x80000000)
#define HPRIME 1000003u
#define SCAP  256

// jnp.logaddexp: max + log1p(exp(-|a-b|)) (all values finite here)
__device__ __forceinline__ float lae(float a, float b) {
  float mx = fmaxf(a, b);
  return mx + log1pf(expf(-fabsf(a - b)));
}
// monotonic float <-> uint mapping for ordering / atomicMax on floats
__device__ __forceinline__ unsigned encf(float x) {
  unsigned v = __float_as_uint(x);
  return (v & 0x80000000u) ? ~v : (v | 0x80000000u);
}
__device__ __forceinline__ float decf(unsigned u) {
  unsigned v = (u & 0x80000000u) ? (u ^ 0x80000000u) : ~u;
  return __uint_as_float(v);
}
__device__ __forceinline__ unsigned lowkey(unsigned h) {
  return 0xFFFFFFFFu - (h ^ 0x80000000u);   // smaller signed hash ranks higher
}

__device__ __forceinline__ int tbl_insert(int* key, int h) {
  unsigned x = (unsigned)h * 2654435761u;
  x ^= x >> 16;
  int j = (int)(((unsigned long long)x * (unsigned long long)TBL) >> 32);
  for (;;) {
    int cur = key[j];
    if (cur == EMPTYK) cur = atomicCAS(&key[j], EMPTYK, h);
    if (cur == EMPTYK || cur == h) return j;
    ++j; if (j == TBL) j = 0;
  }
}

__device__ __forceinline__ unsigned long long shflx64(unsigned long long v, int m) {
  unsigned lo = (unsigned)__shfl_xor((int)(unsigned)v, m, 64);
  unsigned hi = (unsigned)__shfl_xor((int)(unsigned)(v >> 32), m, 64);
  return ((unsigned long long)hi << 32) | lo;
}

// Descending bitonic sort of 64 x u32 across one wave (R3-verified network, R=1)
__device__ __forceinline__ unsigned bitonic64_u32_desc(int ln, unsigned v) {
  #pragma unroll
  for (int size = 2; size <= 64; size <<= 1) {
    #pragma unroll
    for (int stride = size >> 1; stride > 0; stride >>= 1) {
      const unsigned o = (unsigned)__shfl_xor((int)v, stride, 64);
      const bool keepMax = (((ln & size) == 0) == ((ln & stride) == 0));
      v = keepMax ? (v > o ? v : o) : (v < o ? v : o);
    }
  }
  return v;
}

__global__ __launch_bounds__(512, 1)
void ctc_beam_kernel(const float* __restrict__ data,
                     const int* __restrict__ dlen,
                     int* __restrict__ out) {
  // rare-path hash table — touched only on anomalies / overflow
  __shared__ int       tkey[TBL];
  __shared__ unsigned  tmax[TBL];
  __shared__ unsigned  tsum[TBL];
  __shared__ unsigned  tmin[TBL];
  __shared__ unsigned short bp[T_MAX * BEAM];  // backptr: parent|cls<<5|ext<<12
  __shared__ __align__(16) float lpbuf[2][NCLS];
  __shared__ int   bhash[2][BEAM];
  __shared__ float bpb[2][BEAM], bpnb[2][BEAM];
  __shared__ int   blen[2][BEAM], blast[2][BEAM];
  __shared__ float sptot[BEAM], s_pb[BEAM], s_pnb[BEAM], s_pnbm[BEAM];
  __shared__ int   stay_slot[BEAM];
  __shared__ unsigned char mergeTo[BEAM * NCLS];  // 0xFF = not merged
  __shared__ int mergeCnt[BEAM], mergeFrom[BEAM];
  __shared__ unsigned thsub[64];          // [0..31]=stay keys, [32..63]=parentBest
  __shared__ int anom, ovf;
  __shared__ int scnt[2];                 // parity-buffered survivor count
  __shared__ unsigned long long skey[SCAP + 16];  // +16 pad for batched reads
  __shared__ unsigned sidx[SCAP];
  // rare-path selection scratch
  __shared__ unsigned long long wkey[8 * BEAM];
  __shared__ unsigned widx[8 * BEAM];
  __shared__ unsigned sel[BEAM];
  __shared__ int seqbuf[T_MAX];
  __shared__ int flen_s;

  const int tid = threadIdx.x;
  const int b = blockIdx.x;
  int L = dlen[b];
  L = L < 0 ? 0 : (L > T_MAX ? T_MAX : L);

  if (tid < BEAM) {
    bhash[0][tid] = tid;
    bpb[0][tid]   = (tid == 0) ? 0.0f : NEGF;
    bpnb[0][tid]  = NEGF;
    blen[0][tid]  = 0;
    blast[0][tid] = -1;
    mergeCnt[tid] = 0;
  }
  {
    unsigned* mtw = (unsigned*)mergeTo;
    for (int m = tid; m < (BEAM * NCLS) / 4; m += 512) mtw[m] = 0xFFFFFFFFu;
  }
  if (tid == 0) { anom = 0; ovf = 0; scnt[0] = 0; scnt[1] = 0; }
  if (tid < NCLS && L > 0) lpbuf[0][tid] = data[(size_t)b * NCLS + tid];
  __syncthreads();

  int cb = 0;
  for (int t = 0; t < L; ++t) {
    const int par = t & 1;
    const bool haspre = (tid >= 256) && (tid < 256 + NCLS) && (t + 1 < L);
    float pre = 0.0f;
    if (haspre) pre = data[((size_t)(t + 1) * BATCH + b) * NCLS + (tid - 256)];
    float* lpc = lpbuf[par];

    // ======== phase D: stays + exact merge detection + thsub hi-half clear ====
    if (tid < BEAM) {
      const float pbv = bpb[cb][tid], pnbv = bpnb[cb][tid];
      const float pt = lae(pbv, pnbv);
      sptot[tid] = pt;
      s_pb[tid]  = pt + lpc[0];
      const int lsti = blast[cb][tid];
      s_pnb[tid] = pnbv + ((lsti >= 0) ? lpc[lsti] : NEGF);
      thsub[32 + tid] = 0u;
    }
    for (int k = tid; k < BEAM * BEAM; k += 512) {
      const int j = k >> 5, i2 = k & 31;
      const unsigned hj = (unsigned)bhash[cb][j];
      const unsigned hip = (unsigned)bhash[cb][i2] * HPRIME;
      const unsigned c = hj - hip - 1u;
      if (c < (unsigned)NCLS) {                 // extend(i2,c) merges stay j
        atomicAdd(&mergeCnt[j], 1);
        mergeFrom[j] = (i2 << 8) | (int)c;
        mergeTo[i2 * NCLS + (int)c] = (unsigned char)j;
      }
      if (j < i2) {                              // extend-extend collision?
        const unsigned d = (hj - (unsigned)bhash[cb][i2]) * HPRIME;
        if (d + 127u <= 254u) anom = 1;
      }
    }
    __syncthreads();  // A

    // ======== phase K: extend keys + per-parent best + stay keys ========
    const int i  = tid >> 4;
    const int c0 = (tid & 15) << 3;
    unsigned long long k8[8];
    {
      const float pbi = bpb[cb][i];
      const float pti = sptot[i];
      const int   lsti = blast[cb][i];
      const unsigned hb = (unsigned)bhash[cb][i] * HPRIME;
      const float4 l0 = ((const float4*)(lpc + c0))[0];
      const float4 l1 = ((const float4*)(lpc + c0))[1];
      const float lv[8] = {l0.x, l0.y, l0.z, l0.w, l1.x, l1.y, l1.z, l1.w};
      const unsigned m0 = ((const unsigned*)&mergeTo[i * NCLS + c0])[0];
      const unsigned m1 = ((const unsigned*)&mergeTo[i * NCLS + c0])[1];
      unsigned pbest = 0u;
      #pragma unroll
      for (int k = 0; k < 8; ++k) {
        const int c = c0 + k;
        const unsigned mb = ((k < 4 ? (m0 >> (8 * k)) : (m1 >> (8 * (k - 4)))) & 0xFFu);
        const float x = (c == 0) ? NEGF : (((c == lsti) ? pbi : pti) + lv[k]);
        const float tot = fmaxf(x, NEGF);   // == lae(NEGF,x) bitwise
        const unsigned h = hb + (unsigned)(c + 1);
        unsigned long long key =
            ((unsigned long long)encf(tot) << 32) |
            (unsigned long long)lowkey(h);
        if (mb != 0xFFu || c == 0) key = 0ull;   // merged into a stay, or blank
        k8[k] = key;
        const unsigned e32 = (unsigned)(key >> 32);
        pbest = pbest > e32 ? pbest : e32;
      }
      atomicMax(&thsub[32 + i], pbest);
    }
    if (tid < BEAM) {
      const int j = tid;
      if (mergeCnt[j] > 1) anom = 1;
      float pnbm;
      if (mergeCnt[j] == 1) {
        const int mf = mergeFrom[j];
        const int mi = mf >> 8, mc = mf & 255;
        const float e = (mc == 0) ? NEGF
            : (((mc == blast[cb][mi]) ? bpb[cb][mi] : sptot[mi]) + lpc[mc]);
        const float a = s_pnb[j];
        const float m = fmaxf(a, e);
        const float s = expf(a - m) + expf(e - m);  // stay term first (ref order)
        pnbm = m + logf(s);
      } else {
        pnbm = s_pnb[j];
      }
      s_pnbm[j] = pnbm;
      thsub[j] = encf(lae(s_pb[j], pnbm));
    }
    if (tid == 511) scnt[par ^ 1] = 0;   // reset next step's survivor counter
    __syncthreads();  // B

    const bool an = (anom != 0);
    bool dorare = an;
    if (!an) {
      // ======== phase F: wave-redundant u32 bitonic theta + filter/compact ====
      const int ln = tid & 63;
      const unsigned sorted = bitonic64_u32_desc(ln, thsub[ln]);
      const unsigned thr = (unsigned)__shfl((int)sorted, 31, 64);  // 32nd largest

      int myn = 0;
      #pragma unroll
      for (int k = 0; k < 8; ++k) myn += ((unsigned)(k8[k] >> 32) >= thr) ? 1 : 0;
      const bool stayS = (tid < BEAM) && (thsub[tid] >= thr);
      myn += stayS ? 1 : 0;
      if (myn) {
        int o = atomicAdd(&scnt[par], myn);
        if (o + myn <= SCAP) {
          #pragma unroll
          for (int k = 0; k < 8; ++k) {
            if ((unsigned)(k8[k] >> 32) >= thr) {
              skey[o] = k8[k];
              sidx[o] = (unsigned)(BEAM + i * NCLS + (c0 + k));
              ++o;
            }
          }
          if (stayS) {
            skey[o] = ((unsigned long long)thsub[tid] << 32) |
                      (unsigned long long)lowkey((unsigned)bhash[cb][tid]);
            sidx[o] = (unsigned)tid;
          }
        } else ovf = 1;
      }
      __syncthreads();  // D
      dorare = (ovf != 0);
    }

    if (!dorare) {
      // ======== phase R: rank-by-count + update; idle threads do housekeeping ==
      const int scr = scnt[par];
      if (tid < scr) {                           // scr <= 256: rankers are tid<256
        const unsigned long long kq = skey[tid];
        int rank = 0;
        for (int p0 = 0; p0 < scr; p0 += 16) {
          #pragma unroll
          for (int pp = 0; pp < 16; ++pp) {
            const unsigned long long kp = skey[p0 + pp];   // padded, in-bounds
            rank += ((p0 + pp) < scr && kp > kq) ? 1 : 0;
          }
        }
        if (rank < BEAM) {
          const int j = rank;
          const unsigned s = sidx[tid];
          int nh, p, cls, ex; float npb, npnb;
          if (s < BEAM) {                     // stay-rooted segment
            p = (int)s; cls = 0; ex = 0;
            nh = bhash[cb][p];
            npb = s_pb[p];
            npnb = s_pnbm[p];
          } else {                            // standalone extend
            const unsigned q = s - BEAM;
            p = (int)(q >> 7); cls = (int)(q & 127); ex = 1;
            nh = (int)((unsigned)bhash[cb][p] * HPRIME + (unsigned)(cls + 1));
            npb = NEGF;
            npnb = (cls == 0) ? NEGF
                 : (((cls == blast[cb][p]) ? bpb[cb][p] : sptot[p]) + lpc[cls]);
          }
          const int plen = blen[cb][p], plast = blast[cb][p];
          const int nb = cb ^ 1;
          bhash[nb][j] = nh; bpb[nb][j] = npb; bpnb[nb][j] = npnb;
          blen[nb][j]  = plen + ex;
          blast[nb][j] = ex ? cls : plast;
          bp[t * BEAM + j] = (unsigned short)(p | (cls << 5) | (ex << 12));
        }
      }
      if (tid >= 256) {                          // housekeeping for next step
        unsigned* mtw = (unsigned*)mergeTo;
        const int base = tid - 256;
        #pragma unroll
        for (int m = 0; m < 4; ++m) mtw[base + m * 256] = 0xFFFFFFFFu;
        if (haspre) lpbuf[par ^ 1][tid - 256] = pre;
      }
      if (tid >= 64 && tid < 64 + BEAM) mergeCnt[tid - 64] = 0;
      __syncthreads();  // E
    } else {
      // ================= RARE PATH: full hash table (proven R1 semantics) =====
      for (int m = tid; m < TBL; m += 512) {
        tkey[m] = EMPTYK; tmax[m] = 0u; tsum[m] = 0u; tmin[m] = 0xFFFFFFFFu;
      }
      __syncthreads();

      int eslot[8]; float ex_[8];
      {
        const float pbi = bpb[cb][i];
        const float pti = sptot[i];
        const int   lsti = blast[cb][i];
        const unsigned hb = (unsigned)bhash[cb][i] * HPRIME;
        #pragma unroll
        for (int k = 0; k < 8; ++k) {
          const int c = c0 + k;
          int h = (int)(hb + (unsigned)(c + 1));
          if (h == EMPTYK) h = (int)0x80000001u;
          const float x = (c == 0) ? NEGF : (((c == lsti) ? pbi : pti) + lpc[c]);
          const int s = tbl_insert(tkey, h);
          atomicMax(&tmax[s], encf(x));
          atomicMin(&tmin[s], (unsigned)(BEAM + i * NCLS + c));
          eslot[k] = s; ex_[k] = x;
        }
      }
      if (tid < BEAM) {
        const int s = tbl_insert(tkey, bhash[cb][tid]);
        atomicMax(&tmax[s], encf(s_pnb[tid]));
        atomicMin(&tmin[s], (unsigned)tid);
        stay_slot[tid] = s;
      }
      __syncthreads();

      #pragma unroll
      for (int k = 0; k < 8; ++k) {
        const int s = eslot[k];
        atomicAdd((float*)&tsum[s], expf(ex_[k] - decf(tmax[s])));
      }
      if (tid < BEAM) {
        const int s = stay_slot[tid];
        atomicAdd((float*)&tsum[s], expf(s_pnb[tid] - decf(tmax[s])));
      }
      __syncthreads();

      for (int m = tid; m < TBL; m += 512) {
        if (tkey[m] != EMPTYK) {
          const float mm = decf(tmax[m]);
          const float ss = __uint_as_float(tsum[m]);
          const float pnbm = mm + logf(ss);
          tmax[m] = __float_as_uint(pnbm);
          tsum[m] = encf(lae(NEGF, pnbm));
        }
      }
      __syncthreads();
      if (tid < BEAM) {
        const int s = stay_slot[tid];
        tsum[s] = encf(lae(s_pb[tid], __uint_as_float(tmax[s])));
      }
      __syncthreads();

      {
        const int wv = tid >> 6, ln = tid & 63;
        const int base = wv * (TBL / 8) + ln * (TBL / 512);
        unsigned long long kk2[TBL / 512];
        #pragma unroll
        for (int m = 0; m < TBL / 512; ++m) {
          const int idx = base + m;
          if (tkey[idx] != EMPTYK) {
            kk2[m] = ((unsigned long long)tsum[idx] << 32) |
                     (unsigned long long)lowkey((unsigned)tkey[idx]);
          } else kk2[m] = 0ull;
        }
        unsigned cons = 0;
        for (int it = 0; it < BEAM; ++it) {
          unsigned long long best = 0ull; int bi = -1;
          #pragma unroll
          for (int m = 0; m < TBL / 512; ++m)
            if (!((cons >> m) & 1u) && kk2[m] > best) { best = kk2[m]; bi = m; }
          unsigned long long wm = best;
          #pragma unroll
          for (int off = 32; off > 0; off >>= 1) {
            const unsigned long long o = shflx64(wm, off);
            if (o > wm) wm = o;
          }
          const unsigned long long ball = __ballot(best == wm && wm != 0ull);
          const int winner = ball ? (__ffsll((long long)ball) - 1) : -1;
          if (ln == winner) {
            cons |= 1u << bi;
            wkey[wv * BEAM + it] = wm;
            widx[wv * BEAM + it] = (unsigned)(base + bi);
          } else if (winner < 0 && ln == 0) {
            wkey[wv * BEAM + it] = 0ull;
            widx[wv * BEAM + it] = 0xFFFFFFFFu;
          }
        }
      }
      __syncthreads();
      if (tid < 64) {
        unsigned long long kk2[4]; unsigned ii[4];
        #pragma unroll
        for (int m = 0; m < 4; ++m) { kk2[m] = wkey[tid * 4 + m]; ii[m] = widx[tid * 4 + m]; }
        unsigned cons = 0;
        for (int it = 0; it < BEAM; ++it) {
          unsigned long long best = 0ull; int bi = -1;
          #pragma unroll
          for (int m = 0; m < 4; ++m)
            if (!((cons >> m) & 1u) && kk2[m] > best) { best = kk2[m]; bi = m; }
          unsigned long long wm = best;
          #pragma unroll
          for (int off = 32; off > 0; off >>= 1) {
            const unsigned long long o = shflx64(wm, off);
            if (o > wm) wm = o;
          }
          const unsigned long long ball = __ballot(best == wm && wm != 0ull);
          const int winner = ball ? (__ffsll((long long)ball) - 1) : -1;
          if (tid == winner) { cons |= 1u << bi; sel[it] = ii[bi]; }
          else if (winner < 0 && tid == 0) sel[it] = 0xFFFFFFFFu;
        }
      }
      __syncthreads();

      if (tid < BEAM) {
        const int j = tid;
        const unsigned s = sel[j];
        int nh, p, cls, ex; float npb, npnb;
        if (s != 0xFFFFFFFFu) {
          nh = tkey[s];
          npnb = __uint_as_float(tmax[s]);
          npb = NEGF;
          #pragma unroll
          for (int q = 0; q < BEAM; ++q)
            if (stay_slot[q] == (int)s) npb = s_pb[q];
          const unsigned mi = tmin[s];
          ex  = (mi >= BEAM) ? 1 : 0;
          p   = ex ? (int)((mi - BEAM) >> 7) : (int)mi;
          cls = ex ? (int)((mi - BEAM) & 127) : 0;
          p &= 31;
        } else {
          nh = 0x7F000000 + j; npb = NEGF; npnb = NEGF; p = j; cls = 0; ex = 0;
        }
        const int plen = blen[cb][p], plast = blast[cb][p];
        const int nb = cb ^ 1;
        bhash[nb][j] = nh; bpb[nb][j] = npb; bpnb[nb][j] = npnb;
        blen[nb][j]  = plen + ex;
        blast[nb][j] = ex ? cls : plast;
        bp[t * BEAM + j] = (unsigned short)(p | (cls << 5) | (ex << 12));
      }
      // per-step resets (fast path does these in phase R)
      {
        unsigned* mtw = (unsigned*)mergeTo;
        for (int m = tid; m < (BEAM * NCLS) / 4; m += 512) mtw[m] = 0xFFFFFFFFu;
      }
      if (tid >= 64 && tid < 64 + BEAM) mergeCnt[tid - 64] = 0;
      if (tid == 511) { anom = 0; ovf = 0; }
      if (haspre) lpbuf[par ^ 1][tid - 256] = pre;
      __syncthreads();
    }
    cb ^= 1;
  }

  // ---- final top-1 + path reconstruction via backpointers
  if (tid == 0) {
    float bt = -3.4e38f; int bj = 0;
    for (int j = 0; j < BEAM; ++j) {
      const float tt = lae(bpb[cb][j], bpnb[cb][j]);
      if (tt > bt) { bt = tt; bj = j; }   // strict > : lowest index wins ties
    }
    int cur = bj;
    int pos = blen[cb][bj];
    flen_s = pos;
    for (int tt = L - 1; tt >= 0; --tt) {
      const unsigned short e = bp[tt * BEAM + cur];
      const int p = e & 31, cl = (e >> 5) & 127, ex = (e >> 12) & 1;
      if (ex) { --pos; if (pos >= 0) seqbuf[pos] = cl; }
      cur = p;
    }
  }
  __syncthreads();
  const int fl = flen_s;
  for (int k = tid; k < T_MAX; k += 512) {
    out[(size_t)b * T_MAX + k] = (k < fl) ? seqbuf[k] : 0;
  }
}

extern "C" void kernel_launch(void* const* d_in, const int* in_sizes, int n_in,
                              void* d_out, int out_size, void* d_ws, size_t ws_size,
                              hipStream_t stream) {
  const float* data = (const float*)d_in[0];   // [512, 64, 128] f32 log-probs
  const int*   dlen = (const int*)d_in[1];     // [64] int32
  int* out = (int*)d_out;                      // [64, 512] int32
  (void)in_sizes; (void)n_in; (void)out_size; (void)d_ws; (void)ws_size;
  hipLaunchKernelGGL(ctc_beam_kernel, dim3(BATCH), dim3(512), 0, stream,
                     data, dlen, out);
}